// Round 19
// baseline (24.094 us; speedup 1.0000x reference)
//
#include <hip/hip_runtime.h>

typedef _Float16 hh2 __attribute__((ext_vector_type(2)));

#define DH 40
#define DW 40
#define DT 40
#define NC 96
#define NH 6
#define HD 16
#define NTOK 27
#define NVOX (DH * DW * DT)

// Tile: one head x (8 x 8 x 8) voxels. 256 threads, thread = 2 z-adjacent
// voxels (z = 2*za, 2*za+1) -> the 4 halo z-rows per (i,j) are read ONCE
// and shared between both voxels: 36 ds_read_b128/voxel-pair vs 54/voxel.
#define TX 8
#define TY 8
#define TZ 8
#define HX 10
#define HY 10
#define HZ 10
#define NHALO 1000

#define TXN 5
#define TYN 5
#define TZN 5
#define NJOB 750              // 125 tiles x 6 heads
#define GRID 752
#define PER_XCD 94

__device__ __forceinline__ float dot2acc(hh2 a, hh2 b, float c) {
    return __builtin_amdgcn_fdot2(a, b, c, false);
}
__device__ __forceinline__ hh2 pkrtz(float a, float b) {
    return __builtin_bit_cast(hh2, __builtin_amdgcn_cvt_pkrtz(a, b));
}
__device__ __forceinline__ unsigned int pkbits(float a, float b) {
    return __builtin_bit_cast(unsigned int, __builtin_amdgcn_cvt_pkrtz(a, b));
}

// Row n (32B f16) = chunks phys(n,0), phys(n,1).
// phys = (2n+m) ^ ((n>>1)&7): bijective per 128B group (checked n=0..7);
// read-instr slot = (4ly''+4za+2r+m) ^ (2lx''+5ly''+za+(r>>1)) mod 8 —
// the odd 5*ly''+za mix covers all 8 slots x 8 lanes = 2 lanes/bank (free).
__device__ __forceinline__ int phys(int n, int m) {
    return (2 * n + m) ^ ((n >> 1) & 7);
}

union I4H {
    int4 v[2];
    hh2 h[8];
};

__global__ __launch_bounds__(256, 4) void natt_disp_kernel(
    const float* __restrict__ q,
    const float* __restrict__ k,
    const float* __restrict__ rpb,
    float* __restrict__ out)
{
    __shared__ int4 s_k[NHALO * 2];    // 32 KB

    // XCD swizzle: consecutive blockIdx round-robin across 8 XCDs.
    const int job = (blockIdx.x & 7) * PER_XCD + (blockIdx.x >> 3);
    if (job >= NJOB) return;   // block-uniform, before any sync

    const int h    = job % NH;
    const int tile = job / NH;
    const int tz = tile % TZN;
    const int ty = (tile / TZN) % TYN;
    const int tx = tile / (TZN * TYN);
    const int x0 = tx * TX, y0 = ty * TY, z0 = tz * TZ;

    const int tid = threadIdx.x;

    // ---- rpb: block-uniform -> SGPRs; LOG2E folded ----
    const float LOG2E = 1.44269504f;
    float rk[NTOK];
    {
        const float* rb = rpb + h * NTOK;
        #pragma unroll
        for (int kk = 0; kk < NTOK; ++kk) rk[kk] = rb[kk] * LOG2E;
    }

    const float* kh = k + h * HD;

    // ---- Stage k halo, 4-lane coop (R18-proven): 1000 voxels x 4 chunks
    //      = 4000 jobs over 256 threads, 16 rounds.
    #pragma unroll
    for (int it = 0; it < 16; ++it) {
        const int jj = tid + it * 256;
        if (jj < NHALO * 4) {
            const int n = jj >> 2;          // halo voxel
            const int c = jj & 3;           // float4 chunk (16B)
            const int hx = n / (HY * HZ);
            const int r  = n - hx * (HY * HZ);
            const int hy = r / HZ;
            const int hz = r - hy * HZ;
            const int gx = x0 - 1 + hx;
            const int gy = y0 - 1 + hy;
            const int gz = z0 - 1 + hz;
            uint2 w; w.x = 0u; w.y = 0u;
            if (((unsigned)gx < DH) & ((unsigned)gy < DW) & ((unsigned)gz < DT)) {
                const float4 a = *(const float4*)(
                    kh + ((size_t)((gx * DW + gy) * DT + gz)) * NC + c * 4);
                w.x = pkbits(a.x, a.y);
                w.y = pkbits(a.z, a.w);
            }
            ((uint2*)s_k)[phys(n, c >> 1) * 2 + (c & 1)] = w;
        }
    }

    // ---- q fragments for both voxels (direct per-thread loads) ----
    const int za = tid & 3;
    const int ly = (tid >> 2) & 7;
    const int lx = tid >> 5;
    const int vox0 = ((x0 + lx) * DW + (y0 + ly)) * DT + (z0 + 2 * za);
    const int vox1 = vox0 + 1;

    hh2 qh0[8], qh1[8];
    {
        const float4* qv = (const float4*)(q + (size_t)vox0 * NC + h * HD);
        const float4 a = qv[0], b = qv[1], c = qv[2], d = qv[3];
        qh0[0] = pkrtz(a.x, a.y); qh0[1] = pkrtz(a.z, a.w);
        qh0[2] = pkrtz(b.x, b.y); qh0[3] = pkrtz(b.z, b.w);
        qh0[4] = pkrtz(c.x, c.y); qh0[5] = pkrtz(c.z, c.w);
        qh0[6] = pkrtz(d.x, d.y); qh0[7] = pkrtz(d.z, d.w);
    }
    {
        const float4* qv = (const float4*)(q + (size_t)vox1 * NC + h * HD);
        const float4 a = qv[0], b = qv[1], c = qv[2], d = qv[3];
        qh1[0] = pkrtz(a.x, a.y); qh1[1] = pkrtz(a.z, a.w);
        qh1[2] = pkrtz(b.x, b.y); qh1[3] = pkrtz(b.z, b.w);
        qh1[4] = pkrtz(c.x, c.y); qh1[5] = pkrtz(c.z, c.w);
        qh1[6] = pkrtz(d.x, d.y); qh1[7] = pkrtz(d.z, d.w);
    }

    __syncthreads();

    // ---- fused compute, 2 voxels, shared rows. No-max exp2 softmax
    //      (|logit|max ~5.6 << fp32 exp2 range; absmax-proven R9-R18). ----
    const float SC2 = 0.36067376f;   // 0.25 * LOG2E
    float s0 = 0.f, sx0 = 0.f, sy0 = 0.f, sz0 = 0.f;
    float s1 = 0.f, sx1 = 0.f, sy1 = 0.f, sz1 = 0.f;

    #pragma unroll
    for (int i = 0; i < 3; ++i) {
        #pragma unroll
        for (int j = 0; j < 3; ++j) {
            const int base = ((lx + i) * HY + (ly + j)) * HZ + 2 * za;
            const int kb = (i * 3 + j) * 3;
            #pragma unroll
            for (int r = 0; r < 4; ++r) {
                const int n = base + r;
                I4H u;
                u.v[0] = s_k[phys(n, 0)];
                u.v[1] = s_k[phys(n, 1)];
                // voxel0: offset ll = r (r = 0..2)
                if (r <= 2) {
                    float d = 0.0f;
                    d = dot2acc(qh0[0], u.h[0], d);
                    d = dot2acc(qh0[1], u.h[1], d);
                    d = dot2acc(qh0[2], u.h[2], d);
                    d = dot2acc(qh0[3], u.h[3], d);
                    d = dot2acc(qh0[4], u.h[4], d);
                    d = dot2acc(qh0[5], u.h[5], d);
                    d = dot2acc(qh0[6], u.h[6], d);
                    d = dot2acc(qh0[7], u.h[7], d);
                    const float t = exp2f(fmaf(d, SC2, rk[kb + r]));
                    s0 += t;
                    if (i == 0) sx0 -= t; else if (i == 2) sx0 += t;
                    if (j == 0) sy0 -= t; else if (j == 2) sy0 += t;
                    if (r == 0) sz0 -= t; else if (r == 2) sz0 += t;
                }
                // voxel1: offset ll = r-1 (r = 1..3)
                if (r >= 1) {
                    float d = 0.0f;
                    d = dot2acc(qh1[0], u.h[0], d);
                    d = dot2acc(qh1[1], u.h[1], d);
                    d = dot2acc(qh1[2], u.h[2], d);
                    d = dot2acc(qh1[3], u.h[3], d);
                    d = dot2acc(qh1[4], u.h[4], d);
                    d = dot2acc(qh1[5], u.h[5], d);
                    d = dot2acc(qh1[6], u.h[6], d);
                    d = dot2acc(qh1[7], u.h[7], d);
                    const float t = exp2f(fmaf(d, SC2, rk[kb + r - 1]));
                    s1 += t;
                    if (i == 0) sx1 -= t; else if (i == 2) sx1 += t;
                    if (j == 0) sy1 -= t; else if (j == 2) sy1 += t;
                    if (r == 1) sz1 -= t; else if (r == 3) sz1 += t;
                }
            }
        }
    }

    const float i0 = __builtin_amdgcn_rcpf(s0);
    const float i1 = __builtin_amdgcn_rcpf(s1);

    out[((size_t)(h * 3 + 0)) * NVOX + vox0] = sx0 * i0;
    out[((size_t)(h * 3 + 1)) * NVOX + vox0] = sy0 * i0;
    out[((size_t)(h * 3 + 2)) * NVOX + vox0] = sz0 * i0;
    out[((size_t)(h * 3 + 0)) * NVOX + vox1] = sx1 * i1;
    out[((size_t)(h * 3 + 1)) * NVOX + vox1] = sy1 * i1;
    out[((size_t)(h * 3 + 2)) * NVOX + vox1] = sz1 * i1;
}

extern "C" void kernel_launch(void* const* d_in, const int* in_sizes, int n_in,
                              void* d_out, int out_size, void* d_ws, size_t ws_size,
                              hipStream_t stream) {
    const float* q   = (const float*)d_in[0];
    const float* k   = (const float*)d_in[1];
    const float* rpb = (const float*)d_in[2];
    float* out = (float*)d_out;

    natt_disp_kernel<<<GRID, 256, 0, stream>>>(q, k, rpb, out);
}

// Round 20
// 20.514 us; speedup vs baseline: 1.1745x; 1.1745x over previous
//
#include <hip/hip_runtime.h>

typedef _Float16 hh2 __attribute__((ext_vector_type(2)));

#define DH 40
#define DW 40
#define DT 40
#define NC 96
#define NH 6
#define HD 16
#define NTOK 27
#define NVOX (DH * DW * DT)

// Tile: one head x (8 x 8 x 8) voxels, 512 threads, thread = 1 voxel.
// R18 structure verbatim; ONLY change: stores repacked through LDS into
// dwordx4 (16B per lane-address, 384 addrs/block vs 3072 scattered dwords).
#define TX 8
#define TY 8
#define TZ 8
#define HX 10
#define HY 10
#define HZ 10
#define NHALO 1000

#define TXN 5
#define TYN 5
#define TZN 5
#define NJOB 750              // 125 tiles x 6 heads
#define GRID 752
#define PER_XCD 94

__device__ __forceinline__ float dot2acc(hh2 a, hh2 b, float c) {
    return __builtin_amdgcn_fdot2(a, b, c, false);
}
__device__ __forceinline__ hh2 pkrtz(float a, float b) {
    return __builtin_bit_cast(hh2, __builtin_amdgcn_cvt_pkrtz(a, b));
}
__device__ __forceinline__ unsigned int pkbits(float a, float b) {
    return __builtin_bit_cast(unsigned int, __builtin_amdgcn_cvt_pkrtz(a, b));
}

union I4H {
    int4 v[2];
    hh2 h[8];
};

__global__ __launch_bounds__(512, 4) void natt_disp_kernel(
    const float* __restrict__ q,
    const float* __restrict__ k,
    const float* __restrict__ rpb,
    float* __restrict__ out)
{
    // k halo (R18 layout): dense 32B rows, 16B chunks parity-XOR'd by hy&1.
    __shared__ int4 s_k[NHALO * 2];    // 32 KB; reused as store buffer later

    // XCD swizzle: consecutive blockIdx round-robin across 8 XCDs.
    const int job = (blockIdx.x & 7) * PER_XCD + (blockIdx.x >> 3);
    if (job >= NJOB) return;   // block-uniform, before any sync

    const int h    = job % NH;
    const int tile = job / NH;
    const int tz = tile % TZN;
    const int ty = (tile / TZN) % TYN;
    const int tx = tile / (TZN * TYN);
    const int x0 = tx * TX, y0 = ty * TY, z0 = tz * TZ;

    const int tid = threadIdx.x;

    // ---- rpb: block-uniform -> SGPRs; LOG2E folded ----
    const float LOG2E = 1.44269504f;
    float rk[NTOK];
    {
        const float* rb = rpb + h * NTOK;
        #pragma unroll
        for (int kk = 0; kk < NTOK; ++kk) rk[kk] = rb[kk] * LOG2E;
    }

    const float* kh = k + h * HD;

    // ---- Stage k halo, 4-lane coop: 1000 voxels x 4 chunks, 8 rounds ----
    #pragma unroll
    for (int it = 0; it < 8; ++it) {
        const int jj = tid + it * 512;
        if (jj < NHALO * 4) {
            const int n = jj >> 2;
            const int c = jj & 3;
            const int hx = n / (HY * HZ);
            const int r  = n - hx * (HY * HZ);
            const int hy = r / HZ;
            const int hz = r - hy * HZ;
            const int gx = x0 - 1 + hx;
            const int gy = y0 - 1 + hy;
            const int gz = z0 - 1 + hz;
            uint2 w; w.x = 0u; w.y = 0u;
            if (((unsigned)gx < DH) & ((unsigned)gy < DW) & ((unsigned)gz < DT)) {
                const float4 a = *(const float4*)(
                    kh + ((size_t)((gx * DW + gy) * DT + gz)) * NC + c * 4);
                w.x = pkbits(a.x, a.y);
                w.y = pkbits(a.z, a.w);
            }
            const int p = hy & 1;
            ((uint2*)s_k)[((n * 2 + (c >> 1)) ^ p) * 2 + (c & 1)] = w;
        }
    }

    // ---- q fragment direct ----
    const int lz = tid & 7;
    const int ly = (tid >> 3) & 7;
    const int lx = tid >> 6;

    hh2 qh[8];
    {
        const int vox = ((x0 + lx) * DW + (y0 + ly)) * DT + (z0 + lz);
        const float4* qv = (const float4*)(q + (size_t)vox * NC + h * HD);
        const float4 a = qv[0], b = qv[1], c = qv[2], d = qv[3];
        qh[0] = pkrtz(a.x, a.y);
        qh[1] = pkrtz(a.z, a.w);
        qh[2] = pkrtz(b.x, b.y);
        qh[3] = pkrtz(b.z, b.w);
        qh[4] = pkrtz(c.x, c.y);
        qh[5] = pkrtz(c.z, c.w);
        qh[6] = pkrtz(d.x, d.y);
        qh[7] = pkrtz(d.z, d.w);
    }

    __syncthreads();

    // ---- fused: dot -> exp2 (no max; |logit|max ~5.6, absmax-proven) ----
    const float SC2 = 0.36067376f;   // 0.25 * LOG2E
    float sum = 0.f, sx = 0.f, sy = 0.f, sz = 0.f;

    #pragma unroll
    for (int i = 0; i < 3; ++i) {
        #pragma unroll
        for (int j = 0; j < 3; ++j) {
            const int base = ((lx + i) * HY + (ly + j)) * HZ + lz;
            const int p = (ly + j) & 1;
            #pragma unroll
            for (int ll = 0; ll < 3; ++ll) {
                const int n = base + ll;
                I4H u;
                u.v[0] = s_k[(n * 2 + 0) ^ p];
                u.v[1] = s_k[(n * 2 + 1) ^ p];
                float d = 0.0f;
                d = dot2acc(qh[0], u.h[0], d);
                d = dot2acc(qh[1], u.h[1], d);
                d = dot2acc(qh[2], u.h[2], d);
                d = dot2acc(qh[3], u.h[3], d);
                d = dot2acc(qh[4], u.h[4], d);
                d = dot2acc(qh[5], u.h[5], d);
                d = dot2acc(qh[6], u.h[6], d);
                d = dot2acc(qh[7], u.h[7], d);
                const int kk = (i * 3 + j) * 3 + ll;
                const float t = exp2f(fmaf(d, SC2, rk[kk]));
                sum += t;
                if (i == 0) sx -= t; else if (i == 2) sx += t;
                if (j == 0) sy -= t; else if (j == 2) sy += t;
                if (ll == 0) sz -= t; else if (ll == 2) sz += t;
            }
        }
    }

    const float inv = __builtin_amdgcn_rcpf(sum);
    const float ox = sx * inv, oy = sy * inv, oz = sz * inv;

    // ---- coalesced store: repack via LDS, then dwordx4 stores ----
    // sOut[p][v] (p=plane 0..2, v=tile voxel 0..511): 6 KB, aliases s_k
    // (all s_k reads completed; barrier separates).
    __syncthreads();
    float* sOut = (float*)s_k;
    sOut[0 * 512 + tid] = ox;    // consecutive v -> consecutive banks
    sOut[1 * 512 + tid] = oy;
    sOut[2 * 512 + tid] = oz;
    __syncthreads();

    // 384 jobs: (plane p, run) — run = 4 consecutive z of one (lx,ly).
    // LDS read: 16B aligned, lanes stride 16B -> 2 lanes/bank (free).
    // Global: one dwordx4 per lane (16B per address).
    if (tid < 384) {
        const int p   = tid / 128;          // plane 0..2
        const int run = tid - p * 128;      // 0..127
        const int rlx = run >> 4;           // lx 0..7
        const int rly = (run >> 1) & 7;     // ly 0..7
        const int zc  = run & 1;            // z half: 0 or 1 (4 z each)
        const float4 vdat = *(const float4*)&sOut[p * 512 + rlx * 64 + rly * 8 + zc * 4];
        const size_t gidx = (size_t)(h * 3 + p) * NVOX
                          + ((x0 + rlx) * DW + (y0 + rly)) * DT + z0 + zc * 4;
        *(float4*)&out[gidx] = vdat;
    }
}

extern "C" void kernel_launch(void* const* d_in, const int* in_sizes, int n_in,
                              void* d_out, int out_size, void* d_ws, size_t ws_size,
                              hipStream_t stream) {
    const float* q   = (const float*)d_in[0];
    const float* k   = (const float*)d_in[1];
    const float* rpb = (const float*)d_in[2];
    float* out = (float*)d_out;

    natt_disp_kernel<<<GRID, 512, 0, stream>>>(q, k, rpb, out);
}

// Round 21
// 20.293 us; speedup vs baseline: 1.1873x; 1.0109x over previous
//
#include <hip/hip_runtime.h>

typedef _Float16 hh2 __attribute__((ext_vector_type(2)));

#define DH 40
#define DW 40
#define DT 40
#define NC 96
#define NH 6
#define HD 16
#define NTOK 27
#define NVOX (DH * DW * DT)

// Tile: one head x (8 x 8 x 8) voxels, 512 threads, thread = 1 voxel.
// Best measured structure (R18, 20.27us): halo amplification 1.95x,
// 4-lane-coop staging, f16 LDS + v_dot2, fused no-max exp2 softmax.
#define TX 8
#define TY 8
#define TZ 8
#define HX 10
#define HY 10
#define HZ 10
#define NHALO 1000

#define TXN 5
#define TYN 5
#define TZN 5
#define NTILE 125
#define NJOB 750              // 125 tiles x 6 heads
#define GRID 752
#define PER_XCD 94

__device__ __forceinline__ float dot2acc(hh2 a, hh2 b, float c) {
    return __builtin_amdgcn_fdot2(a, b, c, false);
}
__device__ __forceinline__ hh2 pkrtz(float a, float b) {
    return __builtin_bit_cast(hh2, __builtin_amdgcn_cvt_pkrtz(a, b));
}
__device__ __forceinline__ unsigned int pkbits(float a, float b) {
    return __builtin_bit_cast(unsigned int, __builtin_amdgcn_cvt_pkrtz(a, b));
}

union I4H {
    int4 v[2];
    hh2 h[8];
};

// 512 threads, 4 waves/SIMD min -> VGPR cap 128; LDS 32KB -> 5 blocks/CU.
__global__ __launch_bounds__(512, 4) void natt_disp_kernel(
    const float* __restrict__ q,
    const float* __restrict__ k,
    const float* __restrict__ rpb,
    float* __restrict__ out)
{
    // Dense 32B rows, 16B chunks parity-XOR'd by the row's hy&1.
    __shared__ int4 s_k[NHALO * 2];    // 32 KB

    // XCD swizzle: consecutive blockIdx round-robin across 8 XCDs.
    const int job = (blockIdx.x & 7) * PER_XCD + (blockIdx.x >> 3);
    if (job >= NJOB) return;   // block-uniform, before any sync

    const int h    = job % NH;
    const int tile = job / NH;
    const int tz = tile % TZN;
    const int ty = (tile / TZN) % TYN;
    const int tx = tile / (TZN * TYN);
    const int x0 = tx * TX, y0 = ty * TY, z0 = tz * TZ;

    const int tid = threadIdx.x;

    // ---- rpb: block-uniform -> scalar loads into SGPRs ----
    float rk[NTOK];
    {
        const float* rb = rpb + h * NTOK;
        #pragma unroll
        for (int kk = 0; kk < NTOK; ++kk) rk[kk] = rb[kk];
    }

    const float* kh = k + h * HD;

    // ---- Stage k halo, 4-lane coop: lanes 4n..4n+3 read voxel n's 64B.
    //      1000 voxels x 4 chunks = 4000 jobs over 512 threads, 8 rounds.
    #pragma unroll
    for (int it = 0; it < 8; ++it) {
        const int jj = tid + it * 512;
        if (jj < NHALO * 4) {
            const int n = jj >> 2;          // halo voxel
            const int c = jj & 3;           // float4 chunk (16B)
            const int hx = n / (HY * HZ);
            const int r  = n - hx * (HY * HZ);
            const int hy = r / HZ;
            const int hz = r - hy * HZ;
            const int gx = x0 - 1 + hx;
            const int gy = y0 - 1 + hy;
            const int gz = z0 - 1 + hz;
            uint2 w; w.x = 0u; w.y = 0u;
            if (((unsigned)gx < DH) & ((unsigned)gy < DW) & ((unsigned)gz < DT)) {
                const float4 a = *(const float4*)(
                    kh + ((size_t)((gx * DW + gy) * DT + gz)) * NC + c * 4);
                w.x = pkbits(a.x, a.y);
                w.y = pkbits(a.z, a.w);
            }
            const int p = hy & 1;   // row-parity swizzle
            ((uint2*)s_k)[((n * 2 + (c >> 1)) ^ p) * 2 + (c & 1)] = w;
        }
    }

    // ---- q fragment direct ----
    const int lz = tid & 7;
    const int ly = (tid >> 3) & 7;
    const int lx = tid >> 6;
    const int vox = ((x0 + lx) * DW + (y0 + ly)) * DT + (z0 + lz);

    hh2 qh[8];
    {
        const float4* qv = (const float4*)(q + (size_t)vox * NC + h * HD);
        const float4 a = qv[0], b = qv[1], c = qv[2], d = qv[3];
        qh[0] = pkrtz(a.x, a.y);
        qh[1] = pkrtz(a.z, a.w);
        qh[2] = pkrtz(b.x, b.y);
        qh[3] = pkrtz(b.z, b.w);
        qh[4] = pkrtz(c.x, c.y);
        qh[5] = pkrtz(c.z, c.w);
        qh[6] = pkrtz(d.x, d.y);
        qh[7] = pkrtz(d.z, d.w);
    }

    __syncthreads();

    // ---- fused: dot -> exp2 (no max; |logit|max ~5.6, fp32 exp2 finite to
    //      2^127 -> >20x margin; absmax-proven across R9-R20) ----
    const float SC2 = 0.36067376f;   // 0.25 * LOG2E
    const float LOG2E = 1.44269504f;
    float sum = 0.f, sx = 0.f, sy = 0.f, sz = 0.f;

    #pragma unroll
    for (int i = 0; i < 3; ++i) {
        #pragma unroll
        for (int j = 0; j < 3; ++j) {
            const int base = ((lx + i) * HY + (ly + j)) * HZ + lz;
            const int p = (ly + j) & 1;   // row parity of this read row
            #pragma unroll
            for (int ll = 0; ll < 3; ++ll) {
                const int n = base + ll;
                I4H u;
                u.v[0] = s_k[(n * 2 + 0) ^ p];
                u.v[1] = s_k[(n * 2 + 1) ^ p];
                float d = 0.0f;
                d = dot2acc(qh[0], u.h[0], d);
                d = dot2acc(qh[1], u.h[1], d);
                d = dot2acc(qh[2], u.h[2], d);
                d = dot2acc(qh[3], u.h[3], d);
                d = dot2acc(qh[4], u.h[4], d);
                d = dot2acc(qh[5], u.h[5], d);
                d = dot2acc(qh[6], u.h[6], d);
                d = dot2acc(qh[7], u.h[7], d);
                const int kk = (i * 3 + j) * 3 + ll;
                const float t = exp2f(fmaf(d, SC2, rk[kk] * LOG2E));
                sum += t;
                if (i == 0) sx -= t; else if (i == 2) sx += t;
                if (j == 0) sy -= t; else if (j == 2) sy += t;
                if (ll == 0) sz -= t; else if (ll == 2) sz += t;
            }
        }
    }

    const float inv = __builtin_amdgcn_rcpf(sum);

    out[((size_t)(h * 3 + 0)) * NVOX + vox] = sx * inv;
    out[((size_t)(h * 3 + 1)) * NVOX + vox] = sy * inv;
    out[((size_t)(h * 3 + 2)) * NVOX + vox] = sz * inv;
}

extern "C" void kernel_launch(void* const* d_in, const int* in_sizes, int n_in,
                              void* d_out, int out_size, void* d_ws, size_t ws_size,
                              hipStream_t stream) {
    const float* q   = (const float*)d_in[0];
    const float* k   = (const float*)d_in[1];
    const float* rpb = (const float*)d_in[2];
    float* out = (float*)d_out;

    natt_disp_kernel<<<GRID, 512, 0, stream>>>(q, k, rpb, out);
}